// Round 5
// baseline (310.746 us; speedup 1.0000x reference)
//
#include <hip/hip_runtime.h>
#include <stdint.h>
#include <math.h>

// pred_out [8,5,768,768] f32, target_mask [8,1,768,768] i32 (0..3), num_target_classes=4.
#define B_ 8
#define C_ 5
#define H_ 768
#define W_ 768
#define HW_ (H_*W_)
#define HWq (HW_/4)            // float4 per plane = 147456
#define NPIX (B_*HW_)          // 4,718,592
#define NQUAD (NPIX/4)         // 1,179,648
#define TB 8
#define INVAL 0xFFFFFFFFu
#define LN2F 0.69314718056f
#define TILE 64
#define TPR 12
#define TPC 12
#define NTILES (B_*TPR*TPC)    // 1152
#define NNODES (NTILES*256)    // 294912
#define SEAMS_PER_IMG (11*768) // 8448
#define NB_HALF (B_*SEAMS_PER_IMG)   // 67584
#define NB_TOT (2*NB_HALF)           // 135168
#define SEAMBLK (NB_TOT/256)         // 528
#define SBLK 1024                    // k_stats grid
#define NT2 (SBLK*256)               // 262144 threads

// ---------------- compact node union-find (lock-free, agent scope, L2-resident) ------------
static __device__ __forceinline__ unsigned pload(const unsigned* P, unsigned i) {
  return __hip_atomic_load(&P[i], __ATOMIC_RELAXED, __HIP_MEMORY_SCOPE_AGENT);
}
static __device__ unsigned findRootG(unsigned* P, unsigned i) {
  unsigned p = pload(P, i);
  if (p == i) return i;
  unsigned gp = pload(P, p);
  while (p != gp) {
    __hip_atomic_store(&P[i], gp, __ATOMIC_RELAXED, __HIP_MEMORY_SCOPE_AGENT);  // path halving
    i = p; p = gp; gp = pload(P, p);
  }
  return p;
}
// true iff this call linked two distinct components (exactly one real merge)
static __device__ bool uniteG(unsigned* P, unsigned a, unsigned b) {
  a = findRootG(P, a);
  b = findRootG(P, b);
  while (a != b) {
    if (a < b) { unsigned t = a; a = b; b = t; }
    unsigned old = atomicCAS(&P[a], a, b);
    if (old == a) return true;
    a = findRootG(P, old);
    b = findRootG(P, b);
  }
  return false;
}
// ---------------- LDS union-find (workgroup scope) ----------------
static __device__ __forceinline__ unsigned ploadL(const unsigned* P, unsigned i) {
  return __hip_atomic_load(&P[i], __ATOMIC_RELAXED, __HIP_MEMORY_SCOPE_WORKGROUP);
}
static __device__ unsigned findRootL(const unsigned* P, unsigned i) {
  unsigned p = ploadL(P, i);
  while (p != i) { i = p; p = ploadL(P, i); }
  return i;
}
static __device__ void uniteL(unsigned* P, unsigned a, unsigned b) {
  a = findRootL(P, a);
  b = findRootL(P, b);
  while (a != b) {
    if (a < b) { unsigned t = a; a = b; b = t; }
    unsigned old = atomicCAS(&P[a], a, b);
    if (old == a) return;
    a = findRootL(P, old);
    b = findRootL(P, b);
  }
}

// ---------------- k_stats: argmax + per-(t,c) stats + packed cls ----------------
// 16-way replicated LDS histogram (copy = lane&15) -> max 4-way atomic collisions.
// comps: 0=cnt(f32, exact int), 1=sum pred, 2=sum log(clip), 3=sum log1p(-clip)
__global__ __launch_bounds__(256) void k_stats(
    const float4* __restrict__ pred4, const int4* __restrict__ tgt4,
    unsigned* __restrict__ cls4, float* __restrict__ sp)
{
  __shared__ float s_hist[16][41][4];   // 10,496 B
  for (int i = threadIdx.x; i < 16*41*4; i += 256) (&s_hist[0][0][0])[i] = 0.f;
  __syncthreads();
  const int cp = threadIdx.x & 15;
  const int tid = blockIdx.x * 256 + threadIdx.x;

#define DOQUAD(P0, P1, P2, P3, P4, T4, PACKED)                                 \
  {                                                                            \
    PACKED = 0u;                                                               \
    _Pragma("unroll")                                                          \
    for (int j = 0; j < 4; ++j) {                                              \
      float v0 = ((const float*)&(P0))[j];                                     \
      float v1 = ((const float*)&(P1))[j];                                     \
      float v2 = ((const float*)&(P2))[j];                                     \
      float v3 = ((const float*)&(P3))[j];                                     \
      float v4 = ((const float*)&(P4))[j];                                     \
      int tt = ((const int*)&(T4))[j];                                         \
      float best = v0; int bc = 0;                                             \
      if (v1 > best) { best = v1; bc = 1; }                                    \
      if (v2 > best) { best = v2; bc = 2; }                                    \
      if (v3 > best) { best = v3; bc = 3; }                                    \
      if (v4 > best) { best = v4; bc = 4; }                                    \
      unsigned tu = (unsigned)tt; if (tu >= TB) tu = TB - 1;                   \
      float* h = &s_hist[cp][(int)tu * C_ + bc][0];                            \
      atomicAdd(h + 0, 1.0f);                                                  \
      if (bc) {                                                                \
        float pc = fminf(fmaxf(best, 1e-7f), 1.0f - 1e-7f);                    \
        atomicAdd(h + 1, best);                                                \
        atomicAdd(h + 2, __log2f(pc) * LN2F);                                  \
        atomicAdd(h + 3, __log2f(1.0f - pc) * LN2F);                           \
      }                                                                        \
      PACKED |= ((unsigned)bc) << (8 * j);                                     \
    }                                                                          \
  }

  for (int q0 = tid; q0 < NQUAD; q0 += 2 * NT2) {
    int q1 = q0 + NT2;
    bool v1ok = q1 < NQUAD;
    int q1c = v1ok ? q1 : q0;
    int b0 = q0 / HWq, h0 = q0 - b0 * HWq;
    int b1 = q1c / HWq, h1 = q1c - b1 * HWq;
    const float4* ba = pred4 + (size_t)b0 * (C_*HWq) + h0;
    const float4* bb = pred4 + (size_t)b1 * (C_*HWq) + h1;
    // 12 independent 16B loads in flight
    float4 a0 = ba[0], a1 = ba[HWq], a2 = ba[2*HWq], a3 = ba[3*HWq], a4 = ba[4*HWq];
    float4 c0 = bb[0], c1 = bb[HWq], c2 = bb[2*HWq], c3 = bb[3*HWq], c4 = bb[4*HWq];
    int4 ta = tgt4[q0];
    int4 tb = tgt4[q1c];
    unsigned pk0, pk1;
    DOQUAD(a0, a1, a2, a3, a4, ta, pk0)
    cls4[q0] = pk0;
    if (v1ok) {
      DOQUAD(c0, c1, c2, c3, c4, tb, pk1)
      cls4[q1] = pk1;
    }
  }
#undef DOQUAD
  __syncthreads();
  if (threadIdx.x < 160) {
    int slot = threadIdx.x >> 2, comp = threadIdx.x & 3;
    float s = 0.f;
#pragma unroll
    for (int c = 0; c < 16; ++c) s += s_hist[c][slot][comp];
    sp[blockIdx.x * 160 + threadIdx.x] = s;
  }
}

// ---------------- k_ccl: tile-local CCL + border/node emission ----------------
__global__ __launch_bounds__(256) void k_ccl(
    const unsigned* __restrict__ cls4, unsigned short* __restrict__ border,
    unsigned* __restrict__ P2, unsigned* __restrict__ rootcnt)
{
  __shared__ unsigned lab[TILE*TILE];        // 16 KB
  __shared__ unsigned lclsw[TILE*TILE/4];    // 4 KB
  __shared__ unsigned s_rootmin[TILE*TILE];  // 16 KB
  __shared__ unsigned s_rt[4];
  unsigned char* lcls = (unsigned char*)lclsw;

  int blk = blockIdx.x;
  int b = blk / (TPR*TPC);
  int rem = blk - b * (TPR*TPC);
  int ty0 = (rem / TPR) * TILE;
  int tx0 = (rem - (rem / TPR) * TPR) * TILE;

#pragma unroll
  for (int it = 0; it < 16; ++it) s_rootmin[threadIdx.x + it * 256] = INVAL;
  if (threadIdx.x < 4) s_rt[threadIdx.x] = 0u;
  {
    unsigned n = (unsigned)blk * 256u + threadIdx.x;
    P2[n] = n;                                  // this tile's node-UF entries
  }
  // load packed cls tile: row r, 16 u32 per row, uint4 per thread
  {
    int r = threadIdx.x >> 2, cq = threadIdx.x & 3;
    const uint4* src = (const uint4*)(cls4 + ((b * HW_ + (ty0 + r) * W_ + tx0) >> 2));
    uint4 v = src[cq];
    *(uint4*)&lclsw[r * 16 + cq * 4] = v;
  }
  __syncthreads();
#pragma unroll
  for (int it = 0; it < 16; ++it) {
    int li = threadIdx.x + it * 256;
    lab[li] = lcls[li] ? (unsigned)li : INVAL;
  }
  __syncthreads();
  // tile-local union-find (right + down)
#pragma unroll
  for (int it = 0; it < 16; ++it) {
    int li = threadIdx.x + it * 256;
    unsigned char c = lcls[li];
    if (!c) continue;
    int tx = li & 63, ty = li >> 6;
    if (tx < 63 && lcls[li + 1] == c)  uniteL(lab, li, li + 1);
    if (ty < 63 && lcls[li + 64] == c) uniteL(lab, li, li + 64);
  }
  __syncthreads();
  // count local roots per class
#pragma unroll
  for (int it = 0; it < 16; ++it) {
    int li = threadIdx.x + it * 256;
    unsigned char c = lcls[li];
    if (c && lab[li] == (unsigned)li) atomicAdd(&s_rt[c - 1], 1u);
  }
  // border pass -> compact node ids (0-63 top, 64-127 bottom, 128-191 left, 192-255 right)
  {
    int bp = threadIdx.x;
    int tx, ty;
    if (bp < 64)       { ty = 0;  tx = bp; }
    else if (bp < 128) { ty = 63; tx = bp - 64; }
    else if (bp < 192) { tx = 0;  ty = bp - 128; }
    else               { tx = 63; ty = bp - 192; }
    int li = ty * 64 + tx;
    unsigned char c = lcls[li];
    unsigned r = 0;
    if (c) {
      r = findRootL(lab, (unsigned)li);
      atomicMin(&s_rootmin[r], (unsigned)bp);
    }
    __syncthreads();
    unsigned sub = c ? s_rootmin[r] : 0u;   // min border index of component: unique per comp
    border[blk * 256 + bp] = (unsigned short)(((unsigned)c << 8) | sub);
  }
  __syncthreads();
  if (threadIdx.x < 4) rootcnt[blk * 4 + threadIdx.x] = s_rt[threadIdx.x];
}

// ---------------- k_seam: node-graph merge across tile seams ----------------
__global__ __launch_bounds__(256) void k_seam(const unsigned short* __restrict__ border,
                                              unsigned* __restrict__ P2,
                                              unsigned* __restrict__ smcnt)
{
  __shared__ unsigned s_sub[4];
  if (threadIdx.x < 4) s_sub[threadIdx.x] = 0u;
  __syncthreads();
  int idx = blockIdx.x * blockDim.x + threadIdx.x;
  if (idx < NB_TOT) {
    int tA, tB, pA, pB;
    if (idx < NB_HALF) {             // down seams
      int b = idx / SEAMS_PER_IMG;
      int r = idx - b * SEAMS_PER_IMG;
      int seam = r / W_;
      int x = r - seam * W_;
      int tj = x >> 6, k = x & 63;
      tA = (b * TPC + seam) * TPR + tj;
      tB = tA + TPR;
      pA = tA * 256 + 64 + k;
      pB = tB * 256 + 0 + k;
    } else {                         // right seams
      int i2 = idx - NB_HALF;
      int b = i2 / SEAMS_PER_IMG;
      int r = i2 - b * SEAMS_PER_IMG;
      int seam = r / H_;
      int y = r - seam * H_;
      int ti = y >> 6, k = y & 63;
      tA = (b * TPC + ti) * TPR + seam;
      tB = tA + 1;
      pA = tA * 256 + 192 + k;
      pB = tB * 256 + 128 + k;
    }
    unsigned a16 = border[pA];
    unsigned b16 = border[pB];
    unsigned ca = a16 >> 8, cb = b16 >> 8;
    if (ca && ca == cb) {
      if (uniteG(P2, (unsigned)tA * 256u + (a16 & 255u),
                     (unsigned)tB * 256u + (b16 & 255u)))
        atomicAdd(&s_sub[ca - 1], 1u);
    }
  }
  __syncthreads();
  if (threadIdx.x < 4) smcnt[blockIdx.x * 4 + threadIdx.x] = s_sub[threadIdx.x];
}

// ---------------- k_final: parallel reduce + scalar math ----------------
__global__ void k_final(const float* __restrict__ sp, const unsigned* __restrict__ rootcnt,
                        const unsigned* __restrict__ smcnt, const int* __restrict__ ntcp,
                        float* __restrict__ out)
{
  __shared__ double shist[160];
  __shared__ unsigned s_nc[4];
  __shared__ unsigned s_sm[4];
  if (threadIdx.x < 4) { s_nc[threadIdx.x] = 0u; s_sm[threadIdx.x] = 0u; }
  __syncthreads();
  if (threadIdx.x < 160) {
    double s = 0.0;
    for (int g = 0; g < SBLK; ++g) s += (double)sp[g * 160 + threadIdx.x];
    shist[threadIdx.x] = s;
  }
  {
    unsigned a = 0;
    for (int j = threadIdx.x; j < NTILES * 4; j += 256) a += rootcnt[j];  // j&3 fixed/thread
    if (a) atomicAdd(&s_nc[threadIdx.x & 3], a);
  }
  {
    unsigned a = 0;
    for (int j = threadIdx.x; j < SEAMBLK * 4; j += 256) a += smcnt[j];
    if (a) atomicAdd(&s_sm[threadIdx.x & 3], a);
  }
  __syncthreads();
  if (threadIdx.x) return;

  int NT = ntcp[0];
  if (NT < 1) NT = 1;
  if (NT > TB) NT = TB;

  double logpc[TB][C_], log1m[TB][C_], spred[TB][C_], cnt[TB][C_];
  unsigned cnti[TB][C_];
  for (int t = 0; t < TB; ++t)
    for (int c = 0; c < C_; ++c) {
      int s = (t * C_ + c) * 4;
      cnti[t][c]  = (unsigned)llrint(shist[s + 0]);
      cnt[t][c]   = (double)cnti[t][c];
      spred[t][c] = shist[s + 1];
      logpc[t][c] = shist[s + 2];
      log1m[t][c] = shist[s + 3];
    }
  unsigned ctot[C_];
  for (int c = 0; c < C_; ++c) {
    unsigned s = 0;
    for (int t = 0; t < TB; ++t) s += cnti[t][c];
    ctot[c] = s;
  }
  unsigned ncomp[C_] = {0, 0, 0, 0, 0};
  for (int v = 1; v < C_; ++v) ncomp[v] = s_nc[v - 1] - s_sm[v - 1];

  // ph per predicted class: exact f32 replay incl. int32 wrap of n_comp*last_i
  float ph_tab[C_];
  for (int cc = 0; cc < C_; ++cc) {
    float ph = 0.0f;
    int li = 1;
    for (int v = 1; v < C_; ++v) {
      if (ctot[v] > 0) {
        int prod = (int)((unsigned)ncomp[v] * (unsigned)li);
        float sv = (float)prod;
        float inc = ((cc == v) ? 1.0f : 0.0f) + sv;
        ph = ph + inc;
        li = li + (int)ncomp[v] + ((ctot[v] < (unsigned)NPIX) ? 1 : 0);
      }
    }
    ph_tab[cc] = ph;
  }

  const float EPSF = 1e-7f;
  const double L1 = (double)logf(1.0f - EPSF);
  const double M1 = (double)log1pf(-(1.0f - EPSF));
  const double L0 = (double)logf(EPSF);
  const double M0 = (double)log1pf(-EPSF);
  const double N = (double)NPIX;

  double nt0 = 0; for (int c = 0; c < C_; ++c) nt0 += cnt[0][c];
  double np1 = (double)ctot[0];
  double n11 = cnt[0][0];
  double res = -(n11*L1 + (nt0 - n11)*L0 + (np1 - n11)*M1 + (N - nt0 - np1 + n11)*M0) / N
               + 1.0 - (2.0*n11 + 1.0) / (np1 + nt0 + 1.0);

  for (int t = 1; t < NT; ++t) {
    double ntt = 0; long long ntti = 0;
    for (int c = 0; c < C_; ++c) { ntt += cnt[t][c]; ntti += (long long)cnti[t][c]; }
    if (ntti == 0) continue;
    int idx[C_] = {0, 1, 2, 3, 4};
    for (int i = 1; i < C_; ++i)
      for (int j = i; j > 0 && ph_tab[idx[j]] < ph_tab[idx[j-1]]; --j) {
        int tmp = idx[j]; idx[j] = idx[j-1]; idx[j-1] = tmp;
      }
    long long k = (ntti - 1) / 2;
    float med = ph_tab[idx[C_ - 1]];
    long long cum = 0;
    for (int i = 0; i < C_; ++i) {
      cum += (long long)cnti[t][idx[i]];
      if (cum > k) { med = ph_tab[idx[i]]; break; }
    }
    double A = 0, Bt = 0, inter = 0, sum_p = 0, ex = 0, nfg_t = 0, nfg_all = 0;
    for (int c = 1; c < C_; ++c) {
      if (ph_tab[c] == med) {
        A += logpc[t][c];
        inter += spred[t][c];
        nfg_t += cnt[t][c];
        for (int t2 = 0; t2 < TB; ++t2) {
          nfg_all += cnt[t2][c];
          sum_p += spred[t2][c];
          if (t2 != t) Bt += log1m[t2][c];
        }
      } else {
        ex += spred[t][c];
      }
    }
    double bce  = -(A + Bt + (ntt - nfg_t)*L0 + (N - ntt - (nfg_all - nfg_t))*M0) / N;
    double dice = 1.0 - (2.0*inter + 1.0) / (sum_p + ntt + 1.0);
    res += bce + dice + ex / ntt;
  }

  int nun = 0;
  for (int t = 0; t < NT; ++t) {
    long long s = 0;
    for (int c = 0; c < C_; ++c) s += (long long)cnti[t][c];
    if (s) nun++;
  }
  out[0] = (float)(res / (double)(2 * nun + 1));
}

extern "C" void kernel_launch(void* const* d_in, const int* in_sizes, int n_in,
                              void* d_out, int out_size, void* d_ws, size_t ws_size,
                              hipStream_t stream) {
  const float* pred = (const float*)d_in[0];
  const int* tgt = (const int*)d_in[1];
  const int* ntc = (const int*)d_in[2];
  float* out = (float*)d_out;
  char* ws = (char*)d_ws;
  // ws layout (all 16B-aligned): cls4 | sp | P2 | border | rootcnt | smcnt  (~7.2 MB)
  size_t off = 0;
  unsigned* cls4 = (unsigned*)(ws + off);        off += (size_t)NQUAD * 4;        // 4,718,592
  float* sp = (float*)(ws + off);                off += (size_t)SBLK * 160 * 4;   // 655,360
  unsigned* P2 = (unsigned*)(ws + off);          off += (size_t)NNODES * 4;       // 1,179,648
  unsigned short* border = (unsigned short*)(ws + off); off += (size_t)NTILES * 256 * 2; // 589,824
  unsigned* rootcnt = (unsigned*)(ws + off);     off += (size_t)NTILES * 4 * 4;   // 18,432
  unsigned* smcnt = (unsigned*)(ws + off);       off += (size_t)SEAMBLK * 4 * 4;  // 8,448

  hipLaunchKernelGGL(k_stats, dim3(SBLK), dim3(256), 0, stream,
                     (const float4*)pred, (const int4*)tgt, cls4, sp);
  hipLaunchKernelGGL(k_ccl, dim3(NTILES), dim3(256), 0, stream,
                     cls4, border, P2, rootcnt);
  hipLaunchKernelGGL(k_seam, dim3(SEAMBLK), dim3(256), 0, stream,
                     border, P2, smcnt);
  hipLaunchKernelGGL(k_final, dim3(1), dim3(256), 0, stream,
                     sp, rootcnt, smcnt, ntc, out);
}

// Round 6
// 229.764 us; speedup vs baseline: 1.3525x; 1.3525x over previous
//
#include <hip/hip_runtime.h>
#include <stdint.h>
#include <math.h>

// pred_out [8,5,768,768] f32, target_mask [8,1,768,768] i32 (0..3), num_target_classes=4.
#define B_ 8
#define C_ 5
#define H_ 768
#define W_ 768
#define HW_ (H_*W_)
#define HWq (HW_/4)            // 147456 float4 per plane
#define NPIX (B_*HW_)          // 4,718,592
#define NQUAD (NPIX/4)         // 1,179,648
#define TB 8
#define INVAL 0xFFFFFFFFu
#define LN2F 0.69314718056f
#define BIASF 16.2f
#define TILE 64
#define TPR 12
#define TPC 12
#define NTILES (B_*TPR*TPC)    // 1152
#define NNODES (NTILES*256)    // 294912
#define SEAMS_PER_IMG (11*768) // 8448
#define NB_HALF (B_*SEAMS_PER_IMG)   // 67584
#define NB_TOT (2*NB_HALF)           // 135168
#define SEAMBLK (NB_TOT/256)         // 528
#define SBLK 2304                    // k_stats grid; NQUAD == 2*SBLK*256 exactly
#define NTH (SBLK*256)               // 589824

typedef unsigned long long ull;

// ---------------- compact node union-find (lock-free, agent scope, L2-resident) ------------
static __device__ __forceinline__ unsigned pload(const unsigned* P, unsigned i) {
  return __hip_atomic_load(&P[i], __ATOMIC_RELAXED, __HIP_MEMORY_SCOPE_AGENT);
}
static __device__ unsigned findRootG(unsigned* P, unsigned i) {
  unsigned p = pload(P, i);
  if (p == i) return i;
  unsigned gp = pload(P, p);
  while (p != gp) {
    __hip_atomic_store(&P[i], gp, __ATOMIC_RELAXED, __HIP_MEMORY_SCOPE_AGENT);  // path halving
    i = p; p = gp; gp = pload(P, p);
  }
  return p;
}
static __device__ bool uniteG(unsigned* P, unsigned a, unsigned b) {
  a = findRootG(P, a);
  b = findRootG(P, b);
  while (a != b) {
    if (a < b) { unsigned t = a; a = b; b = t; }
    unsigned old = atomicCAS(&P[a], a, b);
    if (old == a) return true;     // one real merge
    a = findRootG(P, old);
    b = findRootG(P, b);
  }
  return false;
}
// ---------------- LDS union-find with high-16-bit payload (workgroup scope) ----------------
// lab word: [31:16] payload (0xFFFF during unions; min border-pos after), [15:0] parent idx.
static __device__ __forceinline__ unsigned ploadL(const unsigned* P, unsigned i) {
  return __hip_atomic_load(&P[i], __ATOMIC_RELAXED, __HIP_MEMORY_SCOPE_WORKGROUP);
}
static __device__ unsigned findRootL(const unsigned* P, unsigned i) {
  unsigned p = ploadL(P, i) & 0xFFFFu;
  while (p != i) { i = p; p = ploadL(P, i) & 0xFFFFu; }
  return i;
}
static __device__ void uniteL(unsigned* P, unsigned a, unsigned b) {
  a = findRootL(P, a);
  b = findRootL(P, b);
  while (a != b) {
    if (a < b) { unsigned t = a; a = b; b = t; }
    unsigned old = atomicCAS(&P[a], 0xFFFF0000u | a, 0xFFFF0000u | b);
    if (old == (0xFFFF0000u | a)) return;
    a = findRootL(P, old & 0xFFFFu);
    b = findRootL(P, b);
  }
}

// ---------------- k_stats: argmax + packed-u64 histogram + packed cls ----------------
// 16-way replicated LDS histogram; 2 u64 atomics per fg pixel, 1 per bg pixel.
// word A: [63:48] count, [47:0] sum pred * 2^24
// word B: [63:32] sum (logit+16.2) * 2^16, [31:0] sum (-log1p(-pc)) * 2^16
__global__ __launch_bounds__(256) void k_stats(
    const float4* __restrict__ pred4, const int4* __restrict__ tgt4,
    unsigned* __restrict__ cls4, double* __restrict__ sp)
{
  __shared__ ull h[16][41][2];   // 10,496 B
  for (int i = threadIdx.x; i < 16*41*2; i += 256) (&h[0][0][0])[i] = 0ull;
  __syncthreads();
  const int cp = threadIdx.x & 15;
  const int tid = blockIdx.x * 256 + threadIdx.x;

#define DOQUAD(P0, P1, P2, P3, P4, T4, PACKED)                                 \
  {                                                                            \
    PACKED = 0u;                                                               \
    _Pragma("unroll")                                                          \
    for (int j = 0; j < 4; ++j) {                                              \
      float v0 = ((const float*)&(P0))[j];                                     \
      float v1 = ((const float*)&(P1))[j];                                     \
      float v2 = ((const float*)&(P2))[j];                                     \
      float v3 = ((const float*)&(P3))[j];                                     \
      float v4 = ((const float*)&(P4))[j];                                     \
      int tt = ((const int*)&(T4))[j];                                         \
      float best = v0; int bc = 0;                                             \
      if (v1 > best) { best = v1; bc = 1; }                                    \
      if (v2 > best) { best = v2; bc = 2; }                                    \
      if (v3 > best) { best = v3; bc = 3; }                                    \
      if (v4 > best) { best = v4; bc = 4; }                                    \
      unsigned tu = (unsigned)tt; if (tu >= TB) tu = TB - 1;                   \
      ull* hA = &h[cp][(int)tu * C_ + bc][0];                                  \
      if (bc) {                                                                \
        float pc = fminf(fmaxf(best, 1e-7f), 1.0f - 1e-7f);                    \
        float l2p = __log2f(pc);                                               \
        float l2m = __log2f(1.0f - pc);                                        \
        float logit = (l2p - l2m) * LN2F;                                      \
        float mag   = -l2m * LN2F;                                             \
        ull wA = (1ull << 48) | (ull)__float2uint_rn(best * 16777216.0f);      \
        ull wB = ((ull)__float2uint_rn((logit + BIASF) * 65536.0f) << 32)      \
                 | (ull)__float2uint_rn(mag * 65536.0f);                       \
        atomicAdd(hA, wA);                                                     \
        atomicAdd(hA + 1, wB);                                                 \
      } else {                                                                 \
        atomicAdd(hA, 1ull << 48);                                             \
      }                                                                        \
      PACKED |= ((unsigned)bc) << (8 * j);                                     \
    }                                                                          \
  }

  {
    int q0 = tid;
    int q1 = tid + NTH;                    // both always in range: NQUAD == 2*NTH
    int b0 = q0 / HWq, h0 = q0 - b0 * HWq;
    int b1 = q1 / HWq, h1 = q1 - b1 * HWq;
    const float4* ba = pred4 + (size_t)b0 * (C_*HWq) + h0;
    const float4* bb = pred4 + (size_t)b1 * (C_*HWq) + h1;
    float4 a0 = ba[0], a1 = ba[HWq], a2 = ba[2*HWq], a3 = ba[3*HWq], a4 = ba[4*HWq];
    float4 c0 = bb[0], c1 = bb[HWq], c2 = bb[2*HWq], c3 = bb[3*HWq], c4 = bb[4*HWq];
    int4 ta = tgt4[q0];
    int4 tb = tgt4[q1];
    unsigned pk0, pk1;
    DOQUAD(a0, a1, a2, a3, a4, ta, pk0)
    DOQUAD(c0, c1, c2, c3, c4, tb, pk1)
    cls4[q0] = pk0;
    cls4[q1] = pk1;
  }
#undef DOQUAD
  __syncthreads();
  if (threadIdx.x < 160) {
    int slot = threadIdx.x >> 2, comp = threadIdx.x & 3;
    double s = 0.0;
#pragma unroll
    for (int c = 0; c < 16; ++c) {
      ull wA = h[c][slot][0], wB = h[c][slot][1];
      if (comp == 0)      s += (double)(wA >> 48);
      else if (comp == 1) s += (double)(wA & 0xFFFFFFFFFFFFull) * (1.0/16777216.0);
      else if (comp == 2) s += (double)(wB >> 32) * (1.0/65536.0);
      else                s += (double)(wB & 0xFFFFFFFFull) * (1.0/65536.0);
    }
    sp[(size_t)blockIdx.x * 160 + threadIdx.x] = s;
  }
}

// ---------------- k_ccl: tile-local CCL (20.3 KB LDS) + border/node emission ----------------
__global__ __launch_bounds__(256) void k_ccl(
    const unsigned* __restrict__ cls4, unsigned short* __restrict__ border,
    unsigned* __restrict__ P2, unsigned* __restrict__ rootcnt)
{
  __shared__ unsigned lab[TILE*TILE];        // 16 KB (payload in high 16 bits)
  __shared__ unsigned lclsw[TILE*TILE/4];    // 4 KB
  __shared__ unsigned s_rt[4];
  unsigned char* lcls = (unsigned char*)lclsw;

  int blk = blockIdx.x;
  int b = blk / (TPR*TPC);
  int rem = blk - b * (TPR*TPC);
  int ty0 = (rem / TPR) * TILE;
  int tx0 = (rem - (rem / TPR) * TPR) * TILE;

  if (threadIdx.x < 4) s_rt[threadIdx.x] = 0u;
  {
    unsigned n = (unsigned)blk * 256u + threadIdx.x;
    P2[n] = n;                                  // this tile's 256 node-UF entries
  }
  // load packed cls tile: row r, 16 u32 per row, uint4 per thread
  {
    int r = threadIdx.x >> 2, cq = threadIdx.x & 3;
    const uint4* src = (const uint4*)(cls4 + ((b * HW_ + (ty0 + r) * W_ + tx0) >> 2));
    uint4 v = src[cq];
    *(uint4*)&lclsw[r * 16 + cq * 4] = v;
  }
  __syncthreads();
#pragma unroll
  for (int it = 0; it < 16; ++it) {
    int li = threadIdx.x + it * 256;
    lab[li] = lcls[li] ? (0xFFFF0000u | (unsigned)li) : INVAL;
  }
  __syncthreads();
  // tile-local union-find (right + down)
#pragma unroll
  for (int it = 0; it < 16; ++it) {
    int li = threadIdx.x + it * 256;
    unsigned char c = lcls[li];
    if (!c) continue;
    int tx = li & 63, ty = li >> 6;
    if (tx < 63 && lcls[li + 1] == c)  uniteL(lab, li, li + 1);
    if (ty < 63 && lcls[li + 64] == c) uniteL(lab, li, li + 64);
  }
  __syncthreads();
  // count local roots per class (root iff low16 == self)
#pragma unroll
  for (int it = 0; it < 16; ++it) {
    int li = threadIdx.x + it * 256;
    unsigned char c = lcls[li];
    if (c && (lab[li] & 0xFFFFu) == (unsigned)li) atomicAdd(&s_rt[c - 1], 1u);
  }
  // border pass: min border-pos into root's high bits (phase-separated from CAS)
  int bp = threadIdx.x;
  int tx, ty;
  if (bp < 64)       { ty = 0;  tx = bp; }
  else if (bp < 128) { ty = 63; tx = bp - 64; }
  else if (bp < 192) { tx = 0;  ty = bp - 128; }
  else               { tx = 63; ty = bp - 192; }
  int li = ty * 64 + tx;
  unsigned char c = lcls[li];
  unsigned r = 0;
  if (c) {
    r = findRootL(lab, (unsigned)li);
    atomicMin(&lab[r], ((unsigned)bp << 16) | r);   // preserves low16=r, root-ness intact
  }
  __syncthreads();
  unsigned sub = c ? (lab[r] >> 16) : 0u;           // min border idx of component: unique
  border[blk * 256 + bp] = (unsigned short)(((unsigned)c << 8) | sub);
  if (threadIdx.x < 4) rootcnt[blk * 4 + threadIdx.x] = s_rt[threadIdx.x];
}

// ---------------- k_seam: node-graph merge + sp reduction in idle blocks ----------------
__global__ __launch_bounds__(256) void k_seam(const unsigned short* __restrict__ border,
                                              unsigned* __restrict__ P2,
                                              unsigned* __restrict__ smcnt,
                                              const double* __restrict__ sp,
                                              double* __restrict__ spf)
{
  __shared__ unsigned s_sub[4];
  __shared__ double red[256];
  if (threadIdx.x < 4) s_sub[threadIdx.x] = 0u;
  __syncthreads();
  int idx = blockIdx.x * blockDim.x + threadIdx.x;
  if (idx < NB_TOT) {
    int tA, tB, pA, pB;
    if (idx < NB_HALF) {             // down seams
      int b = idx / SEAMS_PER_IMG;
      int r = idx - b * SEAMS_PER_IMG;
      int seam = r / W_;
      int x = r - seam * W_;
      int tj = x >> 6, k = x & 63;
      tA = (b * TPC + seam) * TPR + tj;
      tB = tA + TPR;
      pA = tA * 256 + 64 + k;
      pB = tB * 256 + 0 + k;
    } else {                         // right seams
      int i2 = idx - NB_HALF;
      int b = i2 / SEAMS_PER_IMG;
      int r = i2 - b * SEAMS_PER_IMG;
      int seam = r / H_;
      int y = r - seam * H_;
      int ti = y >> 6, k = y & 63;
      tA = (b * TPC + ti) * TPR + seam;
      tB = tA + 1;
      pA = tA * 256 + 192 + k;
      pB = tB * 256 + 128 + k;
    }
    unsigned a16 = border[pA];
    unsigned b16 = border[pB];
    unsigned ca = a16 >> 8, cb = b16 >> 8;
    if (ca && ca == cb) {
      if (uniteG(P2, (unsigned)tA * 256u + (a16 & 255u),
                     (unsigned)tB * 256u + (b16 & 255u)))
        atomicAdd(&s_sub[ca - 1], 1u);
    }
  }
  __syncthreads();
  if (threadIdx.x < 4) smcnt[blockIdx.x * 4 + threadIdx.x] = s_sub[threadIdx.x];
  // fold: blocks 0..159 reduce one histogram slot-comp over all SBLK partials
  if (blockIdx.x < 160) {
    double s = 0.0;
    for (int j = threadIdx.x; j < SBLK; j += 256) s += sp[(size_t)j * 160 + blockIdx.x];
    red[threadIdx.x] = s;
    __syncthreads();
    for (int off = 128; off; off >>= 1) {
      if (threadIdx.x < off) red[threadIdx.x] += red[threadIdx.x + off];
      __syncthreads();
    }
    if (threadIdx.x == 0) spf[blockIdx.x] = red[0];
  }
}

// ---------------- k_final: decode + scalar math ----------------
__global__ void k_final(const double* __restrict__ spf, const unsigned* __restrict__ rootcnt,
                        const unsigned* __restrict__ smcnt, const int* __restrict__ ntcp,
                        float* __restrict__ out)
{
  __shared__ double shist[160];
  __shared__ unsigned s_nc[4];
  __shared__ unsigned s_sm[4];
  if (threadIdx.x < 4) { s_nc[threadIdx.x] = 0u; s_sm[threadIdx.x] = 0u; }
  __syncthreads();
  if (threadIdx.x < 160) shist[threadIdx.x] = spf[threadIdx.x];
  {
    unsigned a = 0;
    for (int j = threadIdx.x; j < NTILES * 4; j += 256) a += rootcnt[j];  // j&3 fixed/thread
    if (a) atomicAdd(&s_nc[threadIdx.x & 3], a);
  }
  {
    unsigned a = 0;
    for (int j = threadIdx.x; j < SEAMBLK * 4; j += 256) a += smcnt[j];
    if (a) atomicAdd(&s_sm[threadIdx.x & 3], a);
  }
  __syncthreads();
  if (threadIdx.x) return;

  int NT = ntcp[0];
  if (NT < 1) NT = 1;
  if (NT > TB) NT = TB;

  double logpc[TB][C_], log1m[TB][C_], spred[TB][C_], cnt[TB][C_];
  unsigned cnti[TB][C_];
  const double BIASD = (double)BIASF;
  for (int t = 0; t < TB; ++t)
    for (int c = 0; c < C_; ++c) {
      int s = (t * C_ + c) * 4;
      cnti[t][c]  = (unsigned)llrint(shist[s + 0]);
      cnt[t][c]   = (double)cnti[t][c];
      spred[t][c] = shist[s + 1];
      double logit = shist[s + 2] - BIASD * cnt[t][c];   // un-bias (fg count == cnt for c>=1)
      double mag   = shist[s + 3];
      log1m[t][c] = -mag;
      logpc[t][c] = logit - mag;                          // logpc = logit + log1m
    }
  unsigned ctot[C_];
  for (int c = 0; c < C_; ++c) {
    unsigned s = 0;
    for (int t = 0; t < TB; ++t) s += cnti[t][c];
    ctot[c] = s;
  }
  unsigned ncomp[C_] = {0, 0, 0, 0, 0};
  for (int v = 1; v < C_; ++v) ncomp[v] = s_nc[v - 1] - s_sm[v - 1];

  // ph per predicted class: exact f32 replay incl. int32 wrap of n_comp*last_i
  float ph_tab[C_];
  for (int cc = 0; cc < C_; ++cc) {
    float ph = 0.0f;
    int li = 1;
    for (int v = 1; v < C_; ++v) {
      if (ctot[v] > 0) {
        int prod = (int)((unsigned)ncomp[v] * (unsigned)li);
        float sv = (float)prod;
        float inc = ((cc == v) ? 1.0f : 0.0f) + sv;
        ph = ph + inc;
        li = li + (int)ncomp[v] + ((ctot[v] < (unsigned)NPIX) ? 1 : 0);
      }
    }
    ph_tab[cc] = ph;
  }

  const float EPSF = 1e-7f;
  const double L1 = (double)logf(1.0f - EPSF);
  const double M1 = (double)log1pf(-(1.0f - EPSF));
  const double L0 = (double)logf(EPSF);
  const double M0 = (double)log1pf(-EPSF);
  const double N = (double)NPIX;

  double nt0 = 0; for (int c = 0; c < C_; ++c) nt0 += cnt[0][c];
  double np1 = (double)ctot[0];
  double n11 = cnt[0][0];
  double res = -(n11*L1 + (nt0 - n11)*L0 + (np1 - n11)*M1 + (N - nt0 - np1 + n11)*M0) / N
               + 1.0 - (2.0*n11 + 1.0) / (np1 + nt0 + 1.0);

  for (int t = 1; t < NT; ++t) {
    double ntt = 0; long long ntti = 0;
    for (int c = 0; c < C_; ++c) { ntt += cnt[t][c]; ntti += (long long)cnti[t][c]; }
    if (ntti == 0) continue;
    int idx[C_] = {0, 1, 2, 3, 4};
    for (int i = 1; i < C_; ++i)
      for (int j = i; j > 0 && ph_tab[idx[j]] < ph_tab[idx[j-1]]; --j) {
        int tmp = idx[j]; idx[j] = idx[j-1]; idx[j-1] = tmp;
      }
    long long k = (ntti - 1) / 2;
    float med = ph_tab[idx[C_ - 1]];
    long long cum = 0;
    for (int i = 0; i < C_; ++i) {
      cum += (long long)cnti[t][idx[i]];
      if (cum > k) { med = ph_tab[idx[i]]; break; }
    }
    double A = 0, Bt = 0, inter = 0, sum_p = 0, ex = 0, nfg_t = 0, nfg_all = 0;
    for (int c = 1; c < C_; ++c) {
      if (ph_tab[c] == med) {
        A += logpc[t][c];
        inter += spred[t][c];
        nfg_t += cnt[t][c];
        for (int t2 = 0; t2 < TB; ++t2) {
          nfg_all += cnt[t2][c];
          sum_p += spred[t2][c];
          if (t2 != t) Bt += log1m[t2][c];
        }
      } else {
        ex += spred[t][c];
      }
    }
    double bce  = -(A + Bt + (ntt - nfg_t)*L0 + (N - ntt - (nfg_all - nfg_t))*M0) / N;
    double dice = 1.0 - (2.0*inter + 1.0) / (sum_p + ntt + 1.0);
    res += bce + dice + ex / ntt;
  }

  int nun = 0;
  for (int t = 0; t < NT; ++t) {
    long long s = 0;
    for (int c = 0; c < C_; ++c) s += (long long)cnti[t][c];
    if (s) nun++;
  }
  out[0] = (float)(res / (double)(2 * nun + 1));
}

extern "C" void kernel_launch(void* const* d_in, const int* in_sizes, int n_in,
                              void* d_out, int out_size, void* d_ws, size_t ws_size,
                              hipStream_t stream) {
  const float* pred = (const float*)d_in[0];
  const int* tgt = (const int*)d_in[1];
  const int* ntc = (const int*)d_in[2];
  float* out = (float*)d_out;
  char* ws = (char*)d_ws;
  // ws layout (16B-aligned chunks): cls4 | sp | spf | P2 | border | rootcnt | smcnt (~9.5 MB)
  size_t off = 0;
  unsigned* cls4 = (unsigned*)(ws + off);        off += (size_t)NQUAD * 4;          // 4,718,592
  double* sp = (double*)(ws + off);              off += (size_t)SBLK * 160 * 8;     // 2,949,120
  double* spf = (double*)(ws + off);             off += 160 * 8;                    // 1,280
  unsigned* P2 = (unsigned*)(ws + off);          off += (size_t)NNODES * 4;         // 1,179,648
  unsigned short* border = (unsigned short*)(ws + off); off += (size_t)NTILES * 256 * 2; // 589,824
  unsigned* rootcnt = (unsigned*)(ws + off);     off += (size_t)NTILES * 4 * 4;     // 18,432
  unsigned* smcnt = (unsigned*)(ws + off);       off += (size_t)SEAMBLK * 4 * 4;    // 8,448

  hipLaunchKernelGGL(k_stats, dim3(SBLK), dim3(256), 0, stream,
                     (const float4*)pred, (const int4*)tgt, cls4, sp);
  hipLaunchKernelGGL(k_ccl, dim3(NTILES), dim3(256), 0, stream,
                     cls4, border, P2, rootcnt);
  hipLaunchKernelGGL(k_seam, dim3(SEAMBLK), dim3(256), 0, stream,
                     border, P2, smcnt, sp, spf);
  hipLaunchKernelGGL(k_final, dim3(1), dim3(256), 0, stream,
                     spf, rootcnt, smcnt, ntc, out);
}